// Round 1
// baseline (487.171 us; speedup 1.0000x reference)
//
#include <hip/hip_runtime.h>
#include <hip/hip_bf16.h>
#include <math.h>

#define GH 721
#define GW 1440
#define C_IN 78
#define C_TOT 86
#define NNODES 5882
#define KNEIGH 128
#define M_TOTAL (NNODES * KNEIGH)   // 752896
#define TM 64
#define NBLOCKS (M_TOTAL / TM)      // 11764

typedef __attribute__((ext_vector_type(8))) short bf16x8;
typedef __attribute__((ext_vector_type(4))) float f32x4;

__device__ __forceinline__ unsigned short f2bf(float x) {
    __hip_bfloat16 b = __float2bfloat16(x);
    union { __hip_bfloat16 h; unsigned short u; } cv; cv.h = b; return cv.u;
}

// ---------------- prep kernel: weight repack + feature tables ----------------
// bp1: [3][4][256][8] bf16  (W1, K padded 86->96 with zeros)
// bp2: [8][4][256][8] bf16  (W2)
// latT: [721][2] f32 normalized (sin,cos), lonT: [1440][2], nrm: means[86]+inv[86]
__global__ void prep_kernel(const float* __restrict__ W1, const float* __restrict__ W2,
                            const float* __restrict__ means, const float* __restrict__ stds,
                            unsigned short* __restrict__ bp1, unsigned short* __restrict__ bp2,
                            float* __restrict__ latT, float* __restrict__ lonT,
                            float* __restrict__ nrm)
{
    const int NB1 = 3 * 4 * 256 * 8;   // 24576
    const int NB2 = 8 * 4 * 256 * 8;   // 65536
    const int NTOT = NB1 + NB2 + GH + GW + C_TOT;
    for (int e = blockIdx.x * blockDim.x + threadIdx.x; e < NTOT;
         e += gridDim.x * blockDim.x) {
        if (e < NB1) {
            int j = e & 7, c = (e >> 3) & 255, o = (e >> 11) & 3, s = e >> 13;
            int k = s * 32 + o * 8 + j;
            float v = (k < C_TOT) ? W1[k * 256 + c] : 0.f;
            bp1[e] = f2bf(v);
        } else if (e < NB1 + NB2) {
            int t = e - NB1;
            int j = t & 7, c = (t >> 3) & 255, o = (t >> 11) & 3, s = t >> 13;
            int k = s * 32 + o * 8 + j;
            bp2[t] = f2bf(W2[k * 256 + c]);
        } else if (e < NB1 + NB2 + GH) {
            int h = e - NB1 - NB2;
            float r = (-90.f + 0.25f * (float)h) * 0.017453292519943295f;
            latT[2 * h]     = (sinf(r) - means[78]) / (stds[78] + 1e-7f);
            latT[2 * h + 1] = (cosf(r) - means[79]) / (stds[79] + 1e-7f);
        } else if (e < NB1 + NB2 + GH + GW) {
            int w = e - NB1 - NB2 - GH;
            float r = ((float)w * (360.f / 1439.f)) * 0.017453292519943295f;
            lonT[2 * w]     = (sinf(r) - means[80]) / (stds[80] + 1e-7f);
            lonT[2 * w + 1] = (cosf(r) - means[81]) / (stds[81] + 1e-7f);
        } else {
            int c = e - NB1 - NB2 - GH - GW;
            nrm[c] = means[c];
            nrm[C_TOT + c] = 1.f / (stds[c] + 1e-7f);
        }
    }
}

// ---------------- fused kernel: gather -> GEMM1 -> ReLU+LN -> GEMM2 ----------------
__global__ __launch_bounds__(256, 2)
void fused_kernel(const float* __restrict__ var_grid, const int* __restrict__ idxs,
                  const unsigned short* __restrict__ bp1, const unsigned short* __restrict__ bp2,
                  const float* __restrict__ latT, const float* __restrict__ lonT,
                  const float* __restrict__ nrm,
                  const float* __restrict__ b1, const float* __restrict__ lnS,
                  const float* __restrict__ lnO, const float* __restrict__ b2,
                  float* __restrict__ out)
{
    __shared__ unsigned short x_lds[TM][104];      // gathered inputs, bf16, padded stride
    __shared__ unsigned short h_lds[TM * 256];     // hidden (post-LN) bf16, XOR-swizzled
    __shared__ float red[2][4][TM];                // LN partials [sum/sq][wave][row]
    __shared__ float nM[C_TOT], nI[C_TOT];
    __shared__ int idx_s[TM];

    const int tid  = threadIdx.x;
    const int lane = tid & 63;
    const int wave = tid >> 6;       // 0..3
    const int l15  = lane & 15;
    const int lg   = lane >> 4;      // 0..3 (K-octet / row-quad group)
    const int wbase = wave * 64;     // this wave's output-column base
    const long block0 = (long)blockIdx.x * TM;

    for (int c = tid; c < C_TOT; c += 256) { nM[c] = nrm[c]; nI[c] = nrm[C_TOT + c]; }
    if (tid < TM) idx_s[tid] = idxs[block0 + tid];
    __syncthreads();

    // ---- gather + normalize + pack to bf16 ----
    {
        const int row = tid >> 2, p = tid & 3;     // 4 lanes per row
        const int idx = idx_s[row];
        const int hh = idx / GW;
        const int ww = idx - hh * GW;
        const float* src = var_grid + (long)idx * C_IN;
        unsigned int* xrow = (unsigned int*)&x_lds[row][0];
        #pragma unroll 4
        for (int q = p; q < 48; q += 4) {
            const int c = 2 * q;
            float v0, v1;
            if (q < 39) {
                float2 t2 = *(const float2*)(src + c);
                v0 = (t2.x - nM[c]) * nI[c];
                v1 = (t2.y - nM[c + 1]) * nI[c + 1];
            } else if (q == 39) { v0 = latT[2 * hh]; v1 = latT[2 * hh + 1]; }
            else if (q == 40)   { v0 = lonT[2 * ww]; v1 = lonT[2 * ww + 1]; }
            else if (q == 41)   { v0 = (0.5f - nM[82]) * nI[82]; v1 = (0.f - nM[83]) * nI[83]; }
            else if (q == 42)   { v0 = (0.f - nM[84]) * nI[84];  v1 = (0.f - nM[85]) * nI[85]; }
            else { v0 = 0.f; v1 = 0.f; }   // K padding 86..95
            xrow[q] = ((unsigned int)f2bf(v1) << 16) | (unsigned int)f2bf(v0);
        }
    }
    __syncthreads();

    // ---- GEMM1: x[64x96] @ W1[96x256] -> acc (f32) ----
    f32x4 acc[4][4];
    #pragma unroll
    for (int mf = 0; mf < 4; ++mf)
        #pragma unroll
        for (int nf = 0; nf < 4; ++nf) acc[mf][nf] = (f32x4){0.f, 0.f, 0.f, 0.f};

    #pragma unroll
    for (int s = 0; s < 3; ++s) {
        bf16x8 af[4], bw[4];
        #pragma unroll
        for (int mf = 0; mf < 4; ++mf)
            af[mf] = *(const bf16x8*)&x_lds[mf * 16 + l15][s * 32 + lg * 8];
        #pragma unroll
        for (int nf = 0; nf < 4; ++nf)
            bw[nf] = *(const bf16x8*)(bp1 + ((size_t)((s * 4 + lg) * 256) + wbase + nf * 16 + l15) * 8);
        #pragma unroll
        for (int mf = 0; mf < 4; ++mf)
            #pragma unroll
            for (int nf = 0; nf < 4; ++nf)
                acc[mf][nf] = __builtin_amdgcn_mfma_f32_16x16x32_bf16(af[mf], bw[nf], acc[mf][nf], 0, 0, 0);
    }

    // ---- bias + ReLU + LayerNorm ----
    float b1v[4], lsv[4], lov[4], b2v[4];
    #pragma unroll
    for (int nf = 0; nf < 4; ++nf) {
        int col = wbase + nf * 16 + l15;
        b1v[nf] = b1[col]; lsv[nf] = lnS[col]; lov[nf] = lnO[col]; b2v[nf] = b2[col];
    }

    float sm[4][4], sq[4][4];
    #pragma unroll
    for (int mf = 0; mf < 4; ++mf)
        #pragma unroll
        for (int i = 0; i < 4; ++i) { sm[mf][i] = 0.f; sq[mf][i] = 0.f; }

    #pragma unroll
    for (int mf = 0; mf < 4; ++mf)
        #pragma unroll
        for (int nf = 0; nf < 4; ++nf)
            #pragma unroll
            for (int i = 0; i < 4; ++i) {
                float v = fmaxf(acc[mf][nf][i] + b1v[nf], 0.f);
                acc[mf][nf][i] = v;
                sm[mf][i] += v;
                sq[mf][i] += v * v;
            }

    #pragma unroll
    for (int m = 1; m < 16; m <<= 1)
        #pragma unroll
        for (int mf = 0; mf < 4; ++mf)
            #pragma unroll
            for (int i = 0; i < 4; ++i) {
                sm[mf][i] += __shfl_xor(sm[mf][i], m, 64);
                sq[mf][i] += __shfl_xor(sq[mf][i], m, 64);
            }

    if (l15 == 0) {
        #pragma unroll
        for (int mf = 0; mf < 4; ++mf)
            #pragma unroll
            for (int i = 0; i < 4; ++i) {
                int row = mf * 16 + lg * 4 + i;
                red[0][wave][row] = sm[mf][i];
                red[1][wave][row] = sq[mf][i];
            }
    }
    __syncthreads();

    #pragma unroll
    for (int mf = 0; mf < 4; ++mf)
        #pragma unroll
        for (int i = 0; i < 4; ++i) {
            int row = mf * 16 + lg * 4 + i;
            float tot = red[0][0][row] + red[0][1][row] + red[0][2][row] + red[0][3][row];
            float tq  = red[1][0][row] + red[1][1][row] + red[1][2][row] + red[1][3][row];
            float mean = tot * (1.f / 256.f);
            float var  = tq * (1.f / 256.f) - mean * mean;
            float rs = rsqrtf(var + 1e-5f);
            #pragma unroll
            for (int nf = 0; nf < 4; ++nf) {
                float v = (acc[mf][nf][i] - mean) * rs * lsv[nf] + lov[nf];
                int col = wbase + nf * 16 + l15;
                unsigned off = (unsigned)(row * 512 + col * 2);
                off ^= (unsigned)((row & 7) << 4);       // bank-conflict swizzle
                *(unsigned short*)((char*)h_lds + off) = f2bf(v);
            }
        }
    __syncthreads();

    // ---- GEMM2: hidden[64x256] @ W2[256x256] ----
    #pragma unroll
    for (int mf = 0; mf < 4; ++mf)
        #pragma unroll
        for (int nf = 0; nf < 4; ++nf) acc[mf][nf] = (f32x4){0.f, 0.f, 0.f, 0.f};

    #pragma unroll
    for (int s = 0; s < 8; ++s) {
        bf16x8 af[4], bw[4];
        #pragma unroll
        for (int mf = 0; mf < 4; ++mf) {
            int row = mf * 16 + l15;
            unsigned off = (unsigned)(row * 512 + (s * 32 + lg * 8) * 2);
            off ^= (unsigned)((row & 7) << 4);
            af[mf] = *(const bf16x8*)((char*)h_lds + off);
        }
        #pragma unroll
        for (int nf = 0; nf < 4; ++nf)
            bw[nf] = *(const bf16x8*)(bp2 + ((size_t)((s * 4 + lg) * 256) + wbase + nf * 16 + l15) * 8);
        #pragma unroll
        for (int mf = 0; mf < 4; ++mf)
            #pragma unroll
            for (int nf = 0; nf < 4; ++nf)
                acc[mf][nf] = __builtin_amdgcn_mfma_f32_16x16x32_bf16(af[mf], bw[nf], acc[mf][nf], 0, 0, 0);
    }

    // ---- epilogue: + b2, store f32 ----
    #pragma unroll
    for (int mf = 0; mf < 4; ++mf)
        #pragma unroll
        for (int i = 0; i < 4; ++i) {
            long row_g = block0 + mf * 16 + lg * 4 + i;
            float* po = out + row_g * 256 + wbase;
            #pragma unroll
            for (int nf = 0; nf < 4; ++nf)
                po[nf * 16 + l15] = acc[mf][nf][i] + b2v[nf];
        }
}

extern "C" void kernel_launch(void* const* d_in, const int* in_sizes, int n_in,
                              void* d_out, int out_size, void* d_ws, size_t ws_size,
                              hipStream_t stream) {
    const float* var_grid = (const float*)d_in[0];
    const int*   idxs     = (const int*)d_in[1];
    const float* means    = (const float*)d_in[2];
    const float* stds     = (const float*)d_in[3];
    const float* W1       = (const float*)d_in[4];
    const float* b1       = (const float*)d_in[5];
    const float* lnS      = (const float*)d_in[6];
    const float* lnO      = (const float*)d_in[7];
    const float* W2       = (const float*)d_in[8];
    const float* b2       = (const float*)d_in[9];
    float* out = (float*)d_out;

    char* ws = (char*)d_ws;
    unsigned short* bp1 = (unsigned short*)ws;               // 49152 B
    unsigned short* bp2 = (unsigned short*)(ws + 49152);     // 131072 B -> 180224
    float* latT = (float*)(ws + 180224);                     // 5768 B
    float* lonT = (float*)(ws + 186000);                     // 11520 B
    float* nrm  = (float*)(ws + 197520);                     // 688 B (end ~198208)

    prep_kernel<<<362, 256, 0, stream>>>(W1, W2, means, stds, bp1, bp2, latT, lonT, nrm);
    fused_kernel<<<NBLOCKS, 256, 0, stream>>>(var_grid, idxs, bp1, bp2, latT, lonT, nrm,
                                              b1, lnS, lnO, b2, out);
}